// Round 1
// baseline (671.453 us; speedup 1.0000x reference)
//
#include <hip/hip_runtime.h>

// ---------------------------------------------------------------------------
// GCN 2-layer: h1 = prelu(gcn(x,W1,b1)), h2 = prelu(gcn(h1,W2,b2))
// Strategy: device-built CSR by dst -> pull aggregation (no float atomics),
// fp32 tiled VALU GEMM for X@W^T, bias+PReLU fused into aggregation write.
// ---------------------------------------------------------------------------

static __device__ __forceinline__ float4 ld4(const float* p) { return *(const float4*)p; }

// --- edge_index dtype hedge: detect int64 vs int32 -------------------------
__global__ void k_detect(const int* ei, int* flag) {
    __shared__ int anynz;
    if (threadIdx.x == 0) anynz = 0;
    __syncthreads();
    // If data is int64 (values < 2^31), every odd int32 word is 0.
    if (ei[2 * threadIdx.x + 1] != 0) anynz = 1;
    __syncthreads();
    if (threadIdx.x == 0) *flag = (anynz == 0) ? 1 : 0;
}

__global__ __launch_bounds__(256) void k_repack(const void* ei_raw, int* eint,
                                                const int* flag, int n) {
    int i = blockIdx.x * 256 + threadIdx.x;
    if (i < n) {
        int v;
        if (*flag) v = (int)((const long long*)ei_raw)[i];
        else       v = ((const int*)ei_raw)[i];
        eint[i] = v;
    }
}

// --- degree + CSR build -----------------------------------------------------
__global__ __launch_bounds__(256) void k_init(float* deg, int* cnt, int N) {
    int i = blockIdx.x * 256 + threadIdx.x;
    if (i < N) { deg[i] = 1.0f; cnt[i] = 0; }   // self-loop weight 1
}

__global__ __launch_bounds__(256) void k_count(const int* eint, const float* ew,
                                               float* deg, int* cnt, int E) {
    int e = blockIdx.x * 256 + threadIdx.x;
    if (e < E) {
        int d = eint[E + e];
        atomicAdd(&deg[d], ew[e]);
        atomicAdd(&cnt[d], 1);
    }
}

__global__ __launch_bounds__(256) void k_dinv(float* deg, int N) {
    int i = blockIdx.x * 256 + threadIdx.x;
    if (i < N) { float dg = deg[i]; deg[i] = dg > 0.f ? rsqrtf(dg) : 0.f; }
}

__global__ __launch_bounds__(256) void k_blocksum(const int* cnt, int* bsum, int N) {
    int i = blockIdx.x * 256 + threadIdx.x;
    int v = i < N ? cnt[i] : 0;
    for (int d = 32; d > 0; d >>= 1) v += __shfl_down(v, d, 64);
    __shared__ int wsum[4];
    int lane = threadIdx.x & 63, wid = threadIdx.x >> 6;
    if (lane == 0) wsum[wid] = v;
    __syncthreads();
    if (threadIdx.x == 0) bsum[blockIdx.x] = wsum[0] + wsum[1] + wsum[2] + wsum[3];
}

__global__ __launch_bounds__(512) void k_scan_bsum(int* bsum, int nb) {
    int t = threadIdx.x;
    int v = (t < nb) ? bsum[t] : 0;
    int orig = v;
    int lane = t & 63, wid = t >> 6;
    for (int d = 1; d < 64; d <<= 1) { int n = __shfl_up(v, d, 64); if (lane >= d) v += n; }
    __shared__ int wsum[8];
    if (lane == 63) wsum[wid] = v;
    __syncthreads();
    int woff = 0;
    for (int w = 0; w < 8; ++w) if (w < wid) woff += wsum[w];
    if (t < nb) bsum[t] = v - orig + woff;   // exclusive
}

__global__ __launch_bounds__(256) void k_scan_final(const int* cnt, const int* bsum,
                                                    int* offs, int* cur, int N, int E) {
    int b = blockIdx.x, t = threadIdx.x;
    int i = b * 256 + t;
    int v = (i < N) ? cnt[i] : 0;
    int orig = v;
    int lane = t & 63, wid = t >> 6;
    for (int d = 1; d < 64; d <<= 1) { int n = __shfl_up(v, d, 64); if (lane >= d) v += n; }
    __shared__ int wsum[4];
    if (lane == 63) wsum[wid] = v;
    __syncthreads();
    int woff = bsum[b];
    for (int w = 0; w < 4; ++w) if (w < wid) woff += wsum[w];
    int excl = v - orig + woff;
    if (i < N) { offs[i] = excl; cur[i] = excl; }
    if (i == 0) offs[N] = E;
}

__global__ __launch_bounds__(256) void k_scatter(const int* eint, const float* ew,
                                                 const float* dinv, int* cur,
                                                 int* ssrc, float* snorm, int E) {
    int e = blockIdx.x * 256 + threadIdx.x;
    if (e < E) {
        int s = eint[e], d = eint[E + e];
        int p = atomicAdd(&cur[d], 1);
        ssrc[p]  = s;
        snorm[p] = dinv[s] * ew[e] * dinv[d];
    }
}

// --- fp32 GEMM: H[M,128] = X[M,K] @ W[128,K]^T ------------------------------
// block = 256 threads, tile 64 rows x 128 cols, Kc=32 chunks staged in LDS.
__global__ __launch_bounds__(256) void k_gemm(const float* __restrict__ X,
                                              const float* __restrict__ W,
                                              float* __restrict__ H, int M, int K) {
    __shared__ float Xs[32][64];    // [kk][row]
    __shared__ float Ws[32][128];   // [kk][col]
    int tid = threadIdx.x;
    int brow = blockIdx.x * 64;
    int tr = tid >> 5, tc = tid & 31;     // 8 row-groups x 32 col-groups
    float acc[8][4] = {};
    for (int k0 = 0; k0 < K; k0 += 32) {
        {   // stage X tile (64 rows x 32 k)
            int row = tid >> 2, q = tid & 3;
            int r = brow + row; if (r >= M) r = M - 1;
            const float* src = X + (size_t)r * K + k0 + q * 8;
            float4 a = ld4(src), b = ld4(src + 4);
            int kb = q * 8;
            Xs[kb+0][row] = a.x; Xs[kb+1][row] = a.y; Xs[kb+2][row] = a.z; Xs[kb+3][row] = a.w;
            Xs[kb+4][row] = b.x; Xs[kb+5][row] = b.y; Xs[kb+6][row] = b.z; Xs[kb+7][row] = b.w;
        }
        {   // stage W tile (128 cols x 32 k)
            int col = tid >> 1, h = tid & 1;
            const float* src = W + (size_t)col * K + k0 + h * 16;
            float4 a = ld4(src), b = ld4(src + 4), c = ld4(src + 8), d = ld4(src + 12);
            int kb = h * 16;
            Ws[kb+ 0][col] = a.x; Ws[kb+ 1][col] = a.y; Ws[kb+ 2][col] = a.z; Ws[kb+ 3][col] = a.w;
            Ws[kb+ 4][col] = b.x; Ws[kb+ 5][col] = b.y; Ws[kb+ 6][col] = b.z; Ws[kb+ 7][col] = b.w;
            Ws[kb+ 8][col] = c.x; Ws[kb+ 9][col] = c.y; Ws[kb+10][col] = c.z; Ws[kb+11][col] = c.w;
            Ws[kb+12][col] = d.x; Ws[kb+13][col] = d.y; Ws[kb+14][col] = d.z; Ws[kb+15][col] = d.w;
        }
        __syncthreads();
        #pragma unroll
        for (int kk = 0; kk < 32; ++kk) {
            float4 w4 = *(const float4*)&Ws[kk][tc * 4];
            float4 x0 = *(const float4*)&Xs[kk][tr * 8];
            float4 x1 = *(const float4*)&Xs[kk][tr * 8 + 4];
            float xs[8] = {x0.x, x0.y, x0.z, x0.w, x1.x, x1.y, x1.z, x1.w};
            float wv[4] = {w4.x, w4.y, w4.z, w4.w};
            #pragma unroll
            for (int r = 0; r < 8; ++r)
                #pragma unroll
                for (int c = 0; c < 4; ++c) acc[r][c] += xs[r] * wv[c];
        }
        __syncthreads();
    }
    #pragma unroll
    for (int r = 0; r < 8; ++r) {
        int row = brow + tr * 8 + r;
        if (row < M) {
            float4 v; v.x = acc[r][0]; v.y = acc[r][1]; v.z = acc[r][2]; v.w = acc[r][3];
            *(float4*)(H + (size_t)row * 128 + tc * 4) = v;
        }
    }
}

// --- pull aggregation + bias + PReLU ---------------------------------------
// 32 lanes per node (4 floats each), shfl-broadcast edge batches.
__global__ __launch_bounds__(256) void k_agg(const float* __restrict__ Hlin,
                                             const int* __restrict__ offs,
                                             const int* __restrict__ ssrc,
                                             const float* __restrict__ snorm,
                                             const float* __restrict__ dinv,
                                             const float* __restrict__ bias,
                                             const float* __restrict__ a_ptr,
                                             float* __restrict__ Out, int N) {
    int g = blockIdx.x * 8 + (threadIdx.x >> 5);
    int lane = threadIdx.x & 31;
    if (g >= N) return;
    float alpha = a_ptr[0];
    float di = dinv[g];
    float4 acc = ld4(bias + lane * 4);
    float4 hv  = ld4(Hlin + (size_t)g * 128 + lane * 4);
    float sw = di * di;                       // self-loop norm
    acc.x += hv.x * sw; acc.y += hv.y * sw; acc.z += hv.z * sw; acc.w += hv.w * sw;
    int j0 = offs[g], j1 = offs[g + 1];
    for (int jb = j0; jb < j1; jb += 32) {
        int j = jb + lane;
        int s = 0; float w = 0.f;
        if (j < j1) { s = ssrc[j]; w = snorm[j]; }
        int cnt = j1 - jb; if (cnt > 32) cnt = 32;
        for (int i = 0; i < cnt; ++i) {
            int   sv = __shfl(s, i, 32);
            float wv = __shfl(w, i, 32);
            float4 h4 = ld4(Hlin + (size_t)sv * 128 + lane * 4);
            acc.x += h4.x * wv; acc.y += h4.y * wv; acc.z += h4.z * wv; acc.w += h4.w * wv;
        }
    }
    acc.x = acc.x >= 0.f ? acc.x : alpha * acc.x;
    acc.y = acc.y >= 0.f ? acc.y : alpha * acc.y;
    acc.z = acc.z >= 0.f ? acc.z : alpha * acc.z;
    acc.w = acc.w >= 0.f ? acc.w : alpha * acc.w;
    *(float4*)(Out + (size_t)g * 128 + lane * 4) = acc;
}

// ---------------------------------------------------------------------------
extern "C" void kernel_launch(void* const* d_in, const int* in_sizes, int n_in,
                              void* d_out, int out_size, void* d_ws, size_t ws_size,
                              hipStream_t stream) {
    const float* x  = (const float*)d_in[0];
    const void*  ei = d_in[1];
    const float* ew = (const float*)d_in[2];
    const float* W1 = (const float*)d_in[3];
    const float* b1 = (const float*)d_in[4];
    const float* W2 = (const float*)d_in[5];
    const float* b2 = (const float*)d_in[6];
    const float* ap = (const float*)d_in[7];
    const int N = in_sizes[0] / 256;
    const int E = in_sizes[2];

    float* out1 = (float*)d_out;
    float* out2 = out1 + (size_t)N * 128;

    char* p = (char*)d_ws;
    auto alloc = [&](size_t bytes) { void* r = (void*)p; p += (bytes + 255) & ~(size_t)255; return r; };
    float* deg   = (float*)alloc((size_t)N * 4);          // becomes dinv in-place
    int*   cnt   = (int*)  alloc((size_t)N * 4);
    int*   offs  = (int*)  alloc((size_t)(N + 1) * 4);
    int*   cur   = (int*)  alloc((size_t)N * 4);
    int*   bsum  = (int*)  alloc((size_t)((N + 255) / 256) * 4);
    int*   flag  = (int*)  alloc(256);
    int*   eint  = (int*)  alloc((size_t)2 * E * 4);
    int*   ssrc  = (int*)  alloc((size_t)E * 4);
    float* snorm = (float*)alloc((size_t)E * 4);
    float* hlin  = (float*)alloc((size_t)N * 128 * 4);

    const int nbN = (N + 255) / 256;
    const int nbE = (E + 255) / 256;
    const int nb2E = (2 * E + 255) / 256;

    k_detect<<<1, 256, 0, stream>>>((const int*)ei, flag);
    k_repack<<<nb2E, 256, 0, stream>>>(ei, eint, flag, 2 * E);
    k_init<<<nbN, 256, 0, stream>>>(deg, cnt, N);
    k_count<<<nbE, 256, 0, stream>>>(eint, ew, deg, cnt, E);
    k_blocksum<<<nbN, 256, 0, stream>>>(cnt, bsum, N);
    k_scan_bsum<<<1, 512, 0, stream>>>(bsum, nbN);
    k_scan_final<<<nbN, 256, 0, stream>>>(cnt, bsum, offs, cur, N, E);
    k_dinv<<<nbN, 256, 0, stream>>>(deg, N);
    k_scatter<<<nbE, 256, 0, stream>>>(eint, ew, deg, cur, ssrc, snorm, E);

    const int gb = (N + 63) / 64;
    k_gemm<<<gb, 256, 0, stream>>>(x, W1, hlin, N, 256);
    k_agg<<<(N + 7) / 8, 256, 0, stream>>>(hlin, offs, ssrc, snorm, deg, b1, ap, out1, N);
    k_gemm<<<gb, 256, 0, stream>>>(out1, W2, hlin, N, 128);
    k_agg<<<(N + 7) / 8, 256, 0, stream>>>(hlin, offs, ssrc, snorm, deg, b2, ap, out2, N);
}

// Round 2
// 524.069 us; speedup vs baseline: 1.2812x; 1.2812x over previous
//
#include <hip/hip_runtime.h>

// ---------------------------------------------------------------------------
// GCN 2-layer: h1 = prelu(gcn(x,W1,b1)), h2 = prelu(gcn(h1,W2,b2))
// CSR build with ONE packed 64-bit atomic per edge (deg fixed-point + count,
// returned old value gives the edge's rank -> atomic-free scatter).
// Pull aggregation (no float atomics), fp32 tiled VALU GEMM, bias+PReLU fused.
// ---------------------------------------------------------------------------

static __device__ __forceinline__ float4 ld4(const float* p) { return *(const float4*)p; }

#define DEG_MASK ((1ULL << 40) - 1)

// --- edge_index dtype hedge: detect int64 vs int32 -------------------------
__global__ void k_detect(const int* ei, int* flag) {
    __shared__ int anynz;
    if (threadIdx.x == 0) anynz = 0;
    __syncthreads();
    if (ei[2 * threadIdx.x + 1] != 0) anynz = 1;
    __syncthreads();
    if (threadIdx.x == 0) *flag = (anynz == 0) ? 1 : 0;
}

__global__ __launch_bounds__(256) void k_repack(const void* ei_raw, int* eint,
                                                const int* flag, int n) {
    int i = blockIdx.x * 256 + threadIdx.x;
    if (i < n) {
        int v;
        if (*flag) v = (int)((const long long*)ei_raw)[i];
        else       v = ((const int*)ei_raw)[i];
        eint[i] = v;
    }
}

__global__ __launch_bounds__(256) void k_init(unsigned long long* packed, int N) {
    int i = blockIdx.x * 256 + threadIdx.x;
    if (i < N) packed[i] = 0ULL;
}

// --- one packed atomic per edge: rank + degree accumulate -------------------
__global__ __launch_bounds__(256) void k_count(const int* __restrict__ eint,
                                               const float* __restrict__ ew,
                                               unsigned long long* __restrict__ packed,
                                               int* __restrict__ rank, int E) {
    int base = blockIdx.x * 1024 + threadIdx.x;
    int d[4]; unsigned long long inc[4]; bool ok[4];
    #pragma unroll
    for (int u = 0; u < 4; ++u) {
        int e = base + u * 256;
        ok[u] = e < E;
        if (ok[u]) {
            d[u] = eint[E + e];
            float w = ew[e];
            inc[u] = (1ULL << 40) | (unsigned long long)(w * 4294967296.0f);
        }
    }
    unsigned long long old[4];
    #pragma unroll
    for (int u = 0; u < 4; ++u)
        if (ok[u]) old[u] = atomicAdd(&packed[d[u]], inc[u]);
    #pragma unroll
    for (int u = 0; u < 4; ++u)
        if (ok[u]) rank[base + u * 256] = (int)(old[u] >> 40);
}

__global__ __launch_bounds__(256) void k_dinv(const unsigned long long* packed,
                                              float* dinv, int N) {
    int i = blockIdx.x * 256 + threadIdx.x;
    if (i < N) {
        float dg = 1.0f + (float)(packed[i] & DEG_MASK) * 2.3283064365386963e-10f;
        dinv[i] = rsqrtf(dg);   // dg >= 1 always (self loop)
    }
}

// --- scan of counts (from packed high bits) --------------------------------
__global__ __launch_bounds__(256) void k_blocksum(const unsigned long long* packed,
                                                  int* bsum, int N) {
    int i = blockIdx.x * 256 + threadIdx.x;
    int v = i < N ? (int)(packed[i] >> 40) : 0;
    for (int d = 32; d > 0; d >>= 1) v += __shfl_down(v, d, 64);
    __shared__ int wsum[4];
    int lane = threadIdx.x & 63, wid = threadIdx.x >> 6;
    if (lane == 0) wsum[wid] = v;
    __syncthreads();
    if (threadIdx.x == 0) bsum[blockIdx.x] = wsum[0] + wsum[1] + wsum[2] + wsum[3];
}

__global__ __launch_bounds__(512) void k_scan_bsum(int* bsum, int nb) {
    int t = threadIdx.x;
    int v = (t < nb) ? bsum[t] : 0;
    int orig = v;
    int lane = t & 63, wid = t >> 6;
    for (int d = 1; d < 64; d <<= 1) { int n = __shfl_up(v, d, 64); if (lane >= d) v += n; }
    __shared__ int wsum[8];
    if (lane == 63) wsum[wid] = v;
    __syncthreads();
    int woff = 0;
    for (int w = 0; w < 8; ++w) if (w < wid) woff += wsum[w];
    if (t < nb) bsum[t] = v - orig + woff;   // exclusive
}

__global__ __launch_bounds__(256) void k_scan_final(const unsigned long long* packed,
                                                    const int* bsum,
                                                    int* offs, int N, int E) {
    int b = blockIdx.x, t = threadIdx.x;
    int i = b * 256 + t;
    int v = (i < N) ? (int)(packed[i] >> 40) : 0;
    int orig = v;
    int lane = t & 63, wid = t >> 6;
    for (int d = 1; d < 64; d <<= 1) { int n = __shfl_up(v, d, 64); if (lane >= d) v += n; }
    __shared__ int wsum[4];
    if (lane == 63) wsum[wid] = v;
    __syncthreads();
    int woff = bsum[b];
    for (int w = 0; w < 4; ++w) if (w < wid) woff += wsum[w];
    if (i < N) offs[i] = v - orig + woff;
    if (i == 0) offs[N] = E;
}

// --- atomic-free scatter: position = offs[dst] + rank[e] -------------------
__global__ __launch_bounds__(256) void k_scatter(const int* __restrict__ eint,
                                                 const float* __restrict__ ew,
                                                 const float* __restrict__ dinv,
                                                 const int* __restrict__ offs,
                                                 const int* __restrict__ rank,
                                                 int* __restrict__ ssrc,
                                                 float* __restrict__ snorm, int E) {
    int e = blockIdx.x * 256 + threadIdx.x;
    if (e < E) {
        int s = eint[e], d = eint[E + e];
        int p = offs[d] + rank[e];
        ssrc[p]  = s;
        snorm[p] = dinv[s] * ew[e] * dinv[d];
    }
}

// --- fp32 GEMM: H[M,128] = X[M,K] @ W[128,K]^T ------------------------------
__global__ __launch_bounds__(256) void k_gemm(const float* __restrict__ X,
                                              const float* __restrict__ W,
                                              float* __restrict__ H, int M, int K) {
    __shared__ float Xs[32][64];    // [kk][row]
    __shared__ float Ws[32][128];   // [kk][col]
    int tid = threadIdx.x;
    int brow = blockIdx.x * 64;
    int tr = tid >> 5, tc = tid & 31;     // 8 row-groups x 32 col-groups
    float acc[8][4] = {};
    for (int k0 = 0; k0 < K; k0 += 32) {
        {   // stage X tile (64 rows x 32 k)
            int row = tid >> 2, q = tid & 3;
            int r = brow + row; if (r >= M) r = M - 1;
            const float* src = X + (size_t)r * K + k0 + q * 8;
            float4 a = ld4(src), b = ld4(src + 4);
            int kb = q * 8;
            Xs[kb+0][row] = a.x; Xs[kb+1][row] = a.y; Xs[kb+2][row] = a.z; Xs[kb+3][row] = a.w;
            Xs[kb+4][row] = b.x; Xs[kb+5][row] = b.y; Xs[kb+6][row] = b.z; Xs[kb+7][row] = b.w;
        }
        {   // stage W tile (128 cols x 32 k)
            int col = tid >> 1, h = tid & 1;
            const float* src = W + (size_t)col * K + k0 + h * 16;
            float4 a = ld4(src), b = ld4(src + 4), c = ld4(src + 8), d = ld4(src + 12);
            int kb = h * 16;
            Ws[kb+ 0][col] = a.x; Ws[kb+ 1][col] = a.y; Ws[kb+ 2][col] = a.z; Ws[kb+ 3][col] = a.w;
            Ws[kb+ 4][col] = b.x; Ws[kb+ 5][col] = b.y; Ws[kb+ 6][col] = b.z; Ws[kb+ 7][col] = b.w;
            Ws[kb+ 8][col] = c.x; Ws[kb+ 9][col] = c.y; Ws[kb+10][col] = c.z; Ws[kb+11][col] = c.w;
            Ws[kb+12][col] = d.x; Ws[kb+13][col] = d.y; Ws[kb+14][col] = d.z; Ws[kb+15][col] = d.w;
        }
        __syncthreads();
        #pragma unroll
        for (int kk = 0; kk < 32; ++kk) {
            float4 w4 = *(const float4*)&Ws[kk][tc * 4];
            float4 x0 = *(const float4*)&Xs[kk][tr * 8];
            float4 x1 = *(const float4*)&Xs[kk][tr * 8 + 4];
            float xs[8] = {x0.x, x0.y, x0.z, x0.w, x1.x, x1.y, x1.z, x1.w};
            float wv[4] = {w4.x, w4.y, w4.z, w4.w};
            #pragma unroll
            for (int r = 0; r < 8; ++r)
                #pragma unroll
                for (int c = 0; c < 4; ++c) acc[r][c] += xs[r] * wv[c];
        }
        __syncthreads();
    }
    #pragma unroll
    for (int r = 0; r < 8; ++r) {
        int row = brow + tr * 8 + r;
        if (row < M) {
            float4 v; v.x = acc[r][0]; v.y = acc[r][1]; v.z = acc[r][2]; v.w = acc[r][3];
            *(float4*)(H + (size_t)row * 128 + tc * 4) = v;
        }
    }
}

// --- pull aggregation + bias + PReLU ---------------------------------------
__global__ __launch_bounds__(256) void k_agg(const float* __restrict__ Hlin,
                                             const int* __restrict__ offs,
                                             const int* __restrict__ ssrc,
                                             const float* __restrict__ snorm,
                                             const float* __restrict__ dinv,
                                             const float* __restrict__ bias,
                                             const float* __restrict__ a_ptr,
                                             float* __restrict__ Out, int N) {
    int g = blockIdx.x * 8 + (threadIdx.x >> 5);
    int lane = threadIdx.x & 31;
    if (g >= N) return;
    float alpha = a_ptr[0];
    float di = dinv[g];
    float4 acc = ld4(bias + lane * 4);
    float4 hv  = ld4(Hlin + (size_t)g * 128 + lane * 4);
    float sw = di * di;                       // self-loop norm
    acc.x += hv.x * sw; acc.y += hv.y * sw; acc.z += hv.z * sw; acc.w += hv.w * sw;
    int j0 = offs[g], j1 = offs[g + 1];
    for (int jb = j0; jb < j1; jb += 32) {
        int j = jb + lane;
        int s = 0; float w = 0.f;
        if (j < j1) { s = ssrc[j]; w = snorm[j]; }
        int cnt = j1 - jb; if (cnt > 32) cnt = 32;
        for (int i = 0; i < cnt; ++i) {
            int   sv = __shfl(s, i, 32);
            float wv = __shfl(w, i, 32);
            float4 h4 = ld4(Hlin + (size_t)sv * 128 + lane * 4);
            acc.x += h4.x * wv; acc.y += h4.y * wv; acc.z += h4.z * wv; acc.w += h4.w * wv;
        }
    }
    acc.x = acc.x >= 0.f ? acc.x : alpha * acc.x;
    acc.y = acc.y >= 0.f ? acc.y : alpha * acc.y;
    acc.z = acc.z >= 0.f ? acc.z : alpha * acc.z;
    acc.w = acc.w >= 0.f ? acc.w : alpha * acc.w;
    *(float4*)(Out + (size_t)g * 128 + lane * 4) = acc;
}

// ---------------------------------------------------------------------------
extern "C" void kernel_launch(void* const* d_in, const int* in_sizes, int n_in,
                              void* d_out, int out_size, void* d_ws, size_t ws_size,
                              hipStream_t stream) {
    const float* x  = (const float*)d_in[0];
    const void*  ei = d_in[1];
    const float* ew = (const float*)d_in[2];
    const float* W1 = (const float*)d_in[3];
    const float* b1 = (const float*)d_in[4];
    const float* W2 = (const float*)d_in[5];
    const float* b2 = (const float*)d_in[6];
    const float* ap = (const float*)d_in[7];
    const int N = in_sizes[0] / 256;
    const int E = in_sizes[2];

    float* out1 = (float*)d_out;
    float* out2 = out1 + (size_t)N * 128;

    char* p = (char*)d_ws;
    auto alloc = [&](size_t bytes) { void* r = (void*)p; p += (bytes + 255) & ~(size_t)255; return r; };
    unsigned long long* packed = (unsigned long long*)alloc((size_t)N * 8);
    float* dinv  = (float*)alloc((size_t)N * 4);
    int*   offs  = (int*)  alloc((size_t)(N + 1) * 4);
    int*   bsum  = (int*)  alloc((size_t)((N + 255) / 256) * 4);
    int*   flag  = (int*)  alloc(256);
    int*   eint  = (int*)  alloc((size_t)2 * E * 4);
    int*   rank  = (int*)  alloc((size_t)E * 4);
    int*   ssrc  = (int*)  alloc((size_t)E * 4);
    float* snorm = (float*)alloc((size_t)E * 4);
    float* hlin  = (float*)alloc((size_t)N * 128 * 4);

    const int nbN = (N + 255) / 256;
    const int nbE = (E + 255) / 256;
    const int nb2E = (2 * E + 255) / 256;
    const int nbE4 = (E + 1023) / 1024;

    k_detect<<<1, 256, 0, stream>>>((const int*)ei, flag);
    k_repack<<<nb2E, 256, 0, stream>>>(ei, eint, flag, 2 * E);
    k_init<<<nbN, 256, 0, stream>>>(packed, N);
    k_count<<<nbE4, 256, 0, stream>>>(eint, ew, packed, rank, E);
    k_blocksum<<<nbN, 256, 0, stream>>>(packed, bsum, N);
    k_scan_bsum<<<1, 512, 0, stream>>>(bsum, nbN);
    k_scan_final<<<nbN, 256, 0, stream>>>(packed, bsum, offs, N, E);
    k_dinv<<<nbN, 256, 0, stream>>>(packed, dinv, N);
    k_scatter<<<nbE, 256, 0, stream>>>(eint, ew, dinv, offs, rank, ssrc, snorm, E);

    const int gb = (N + 63) / 64;
    k_gemm<<<gb, 256, 0, stream>>>(x, W1, hlin, N, 256);
    k_agg<<<(N + 7) / 8, 256, 0, stream>>>(hlin, offs, ssrc, snorm, dinv, b1, ap, out1, N);
    k_gemm<<<gb, 256, 0, stream>>>(out1, W2, hlin, N, 128);
    k_agg<<<(N + 7) / 8, 256, 0, stream>>>(hlin, offs, ssrc, snorm, dinv, b2, ap, out2, N);
}

// Round 3
// 514.633 us; speedup vs baseline: 1.3047x; 1.0183x over previous
//
#include <hip/hip_runtime.h>

// ---------------------------------------------------------------------------
// GCN 2-layer: h1 = prelu(gcn(x,W1,b1)), h2 = prelu(gcn(h1,W2,b2))
// CSR build with ONE packed 64-bit atomic per edge (deg fixed-point + count,
// returned old value gives the edge's rank -> atomic-free scatter).
// Pull aggregation with 4x-unrolled gathers (MLP), fp32 tiled VALU GEMM,
// bias+PReLU fused into the aggregation write.
// ---------------------------------------------------------------------------

static __device__ __forceinline__ float4 ld4(const float* p) { return *(const float4*)p; }

#define DEG_MASK ((1ULL << 40) - 1)

// --- edge_index dtype hedge: detect int64 vs int32 -------------------------
__global__ void k_detect(const int* ei, int* flag) {
    __shared__ int anynz;
    if (threadIdx.x == 0) anynz = 0;
    __syncthreads();
    if (ei[2 * threadIdx.x + 1] != 0) anynz = 1;
    __syncthreads();
    if (threadIdx.x == 0) *flag = (anynz == 0) ? 1 : 0;
}

__global__ __launch_bounds__(256) void k_repack(const void* ei_raw, int* eint,
                                                const int* flag, int n) {
    int i = blockIdx.x * 256 + threadIdx.x;
    if (i < n) {
        int v;
        if (*flag) v = (int)((const long long*)ei_raw)[i];
        else       v = ((const int*)ei_raw)[i];
        eint[i] = v;
    }
}

__global__ __launch_bounds__(256) void k_init(unsigned long long* packed, int N) {
    int i = blockIdx.x * 256 + threadIdx.x;
    if (i < N) packed[i] = 0ULL;
}

// --- one packed atomic per edge: rank + degree accumulate -------------------
__global__ __launch_bounds__(256) void k_count(const int* __restrict__ eint,
                                               const float* __restrict__ ew,
                                               unsigned long long* __restrict__ packed,
                                               int* __restrict__ rank, int E) {
    int base = blockIdx.x * 1024 + threadIdx.x;
    int d[4]; unsigned long long inc[4]; bool ok[4];
    #pragma unroll
    for (int u = 0; u < 4; ++u) {
        int e = base + u * 256;
        ok[u] = e < E;
        if (ok[u]) {
            d[u] = eint[E + e];
            float w = ew[e];
            inc[u] = (1ULL << 40) | (unsigned long long)(w * 4294967296.0f);
        }
    }
    unsigned long long old[4];
    #pragma unroll
    for (int u = 0; u < 4; ++u)
        if (ok[u]) old[u] = atomicAdd(&packed[d[u]], inc[u]);
    #pragma unroll
    for (int u = 0; u < 4; ++u)
        if (ok[u]) rank[base + u * 256] = (int)(old[u] >> 40);
}

__global__ __launch_bounds__(256) void k_dinv(const unsigned long long* packed,
                                              float* dinv, int N) {
    int i = blockIdx.x * 256 + threadIdx.x;
    if (i < N) {
        float dg = 1.0f + (float)(packed[i] & DEG_MASK) * 2.3283064365386963e-10f;
        dinv[i] = rsqrtf(dg);   // dg >= 1 always (self loop)
    }
}

// --- scan of counts (from packed high bits) --------------------------------
__global__ __launch_bounds__(256) void k_blocksum(const unsigned long long* packed,
                                                  int* bsum, int N) {
    int i = blockIdx.x * 256 + threadIdx.x;
    int v = i < N ? (int)(packed[i] >> 40) : 0;
    for (int d = 32; d > 0; d >>= 1) v += __shfl_down(v, d, 64);
    __shared__ int wsum[4];
    int lane = threadIdx.x & 63, wid = threadIdx.x >> 6;
    if (lane == 0) wsum[wid] = v;
    __syncthreads();
    if (threadIdx.x == 0) bsum[blockIdx.x] = wsum[0] + wsum[1] + wsum[2] + wsum[3];
}

__global__ __launch_bounds__(512) void k_scan_bsum(int* bsum, int nb) {
    int t = threadIdx.x;
    int v = (t < nb) ? bsum[t] : 0;
    int orig = v;
    int lane = t & 63, wid = t >> 6;
    for (int d = 1; d < 64; d <<= 1) { int n = __shfl_up(v, d, 64); if (lane >= d) v += n; }
    __shared__ int wsum[8];
    if (lane == 63) wsum[wid] = v;
    __syncthreads();
    int woff = 0;
    for (int w = 0; w < 8; ++w) if (w < wid) woff += wsum[w];
    if (t < nb) bsum[t] = v - orig + woff;   // exclusive
}

__global__ __launch_bounds__(256) void k_scan_final(const unsigned long long* packed,
                                                    const int* bsum,
                                                    int* offs, int N, int E) {
    int b = blockIdx.x, t = threadIdx.x;
    int i = b * 256 + t;
    int v = (i < N) ? (int)(packed[i] >> 40) : 0;
    int orig = v;
    int lane = t & 63, wid = t >> 6;
    for (int d = 1; d < 64; d <<= 1) { int n = __shfl_up(v, d, 64); if (lane >= d) v += n; }
    __shared__ int wsum[4];
    if (lane == 63) wsum[wid] = v;
    __syncthreads();
    int woff = bsum[b];
    for (int w = 0; w < 4; ++w) if (w < wid) woff += wsum[w];
    if (i < N) offs[i] = v - orig + woff;
    if (i == 0) offs[N] = E;
}

// --- atomic-free scatter: position = offs[dst] + rank[e] -------------------
// (src, norm) packed into one int2 -> one 8B store per edge.
__global__ __launch_bounds__(256) void k_scatter(const int* __restrict__ eint,
                                                 const float* __restrict__ ew,
                                                 const float* __restrict__ dinv,
                                                 const int* __restrict__ offs,
                                                 const int* __restrict__ rank,
                                                 int2* __restrict__ spair, int E) {
    int e = blockIdx.x * 256 + threadIdx.x;
    if (e < E) {
        int s = eint[e], d = eint[E + e];
        int p = offs[d] + rank[e];
        float nrm = dinv[s] * ew[e] * dinv[d];
        int2 v; v.x = s; v.y = __float_as_int(nrm);
        spair[p] = v;
    }
}

// --- fp32 GEMM: H[M,128] = X[M,K] @ W[128,K]^T ------------------------------
__global__ __launch_bounds__(256) void k_gemm(const float* __restrict__ X,
                                              const float* __restrict__ W,
                                              float* __restrict__ H, int M, int K) {
    __shared__ float Xs[32][64];    // [kk][row]
    __shared__ float Ws[32][128];   // [kk][col]
    int tid = threadIdx.x;
    int brow = blockIdx.x * 64;
    int tr = tid >> 5, tc = tid & 31;     // 8 row-groups x 32 col-groups
    float acc[8][4] = {};
    for (int k0 = 0; k0 < K; k0 += 32) {
        {   // stage X tile (64 rows x 32 k)
            int row = tid >> 2, q = tid & 3;
            int r = brow + row; if (r >= M) r = M - 1;
            const float* src = X + (size_t)r * K + k0 + q * 8;
            float4 a = ld4(src), b = ld4(src + 4);
            int kb = q * 8;
            Xs[kb+0][row] = a.x; Xs[kb+1][row] = a.y; Xs[kb+2][row] = a.z; Xs[kb+3][row] = a.w;
            Xs[kb+4][row] = b.x; Xs[kb+5][row] = b.y; Xs[kb+6][row] = b.z; Xs[kb+7][row] = b.w;
        }
        {   // stage W tile (128 cols x 32 k)
            int col = tid >> 1, h = tid & 1;
            const float* src = W + (size_t)col * K + k0 + h * 16;
            float4 a = ld4(src), b = ld4(src + 4), c = ld4(src + 8), d = ld4(src + 12);
            int kb = h * 16;
            Ws[kb+ 0][col] = a.x; Ws[kb+ 1][col] = a.y; Ws[kb+ 2][col] = a.z; Ws[kb+ 3][col] = a.w;
            Ws[kb+ 4][col] = b.x; Ws[kb+ 5][col] = b.y; Ws[kb+ 6][col] = b.z; Ws[kb+ 7][col] = b.w;
            Ws[kb+ 8][col] = c.x; Ws[kb+ 9][col] = c.y; Ws[kb+10][col] = c.z; Ws[kb+11][col] = c.w;
            Ws[kb+12][col] = d.x; Ws[kb+13][col] = d.y; Ws[kb+14][col] = d.z; Ws[kb+15][col] = d.w;
        }
        __syncthreads();
        #pragma unroll
        for (int kk = 0; kk < 32; ++kk) {
            float4 w4 = *(const float4*)&Ws[kk][tc * 4];
            float4 x0 = *(const float4*)&Xs[kk][tr * 8];
            float4 x1 = *(const float4*)&Xs[kk][tr * 8 + 4];
            float xs[8] = {x0.x, x0.y, x0.z, x0.w, x1.x, x1.y, x1.z, x1.w};
            float wv[4] = {w4.x, w4.y, w4.z, w4.w};
            #pragma unroll
            for (int r = 0; r < 8; ++r)
                #pragma unroll
                for (int c = 0; c < 4; ++c) acc[r][c] += xs[r] * wv[c];
        }
        __syncthreads();
    }
    #pragma unroll
    for (int r = 0; r < 8; ++r) {
        int row = brow + tr * 8 + r;
        if (row < M) {
            float4 v; v.x = acc[r][0]; v.y = acc[r][1]; v.z = acc[r][2]; v.w = acc[r][3];
            *(float4*)(H + (size_t)row * 128 + tc * 4) = v;
        }
    }
}

// --- pull aggregation + bias + PReLU, 4x-unrolled gathers ------------------
__global__ __launch_bounds__(256) void k_agg(const float* __restrict__ Hlin,
                                             const int* __restrict__ offs,
                                             const int2* __restrict__ spair,
                                             const float* __restrict__ dinv,
                                             const float* __restrict__ bias,
                                             const float* __restrict__ a_ptr,
                                             float* __restrict__ Out, int N) {
    int g = blockIdx.x * 8 + (threadIdx.x >> 5);
    int lane = threadIdx.x & 31;
    if (g >= N) return;
    float alpha = a_ptr[0];
    float di = dinv[g];
    float4 acc = ld4(bias + lane * 4);
    float4 hv  = ld4(Hlin + (size_t)g * 128 + lane * 4);
    float sw = di * di;                       // self-loop norm
    acc.x += hv.x * sw; acc.y += hv.y * sw; acc.z += hv.z * sw; acc.w += hv.w * sw;
    int j0 = offs[g], j1 = offs[g + 1];
    for (int jb = j0; jb < j1; jb += 32) {
        int j = jb + lane;
        int s = 0; float w = 0.f;
        if (j < j1) { int2 sp = spair[j]; s = sp.x; w = __int_as_float(sp.y); }
        int cnt = j1 - jb; if (cnt > 32) cnt = 32;
        int cnt4 = (cnt + 3) & ~3;
        for (int i = 0; i < cnt4; i += 4) {
            int   s0 = __shfl(s, i,     32), s1 = __shfl(s, i + 1, 32);
            int   s2 = __shfl(s, i + 2, 32), s3 = __shfl(s, i + 3, 32);
            float w0 = __shfl(w, i,     32), w1 = __shfl(w, i + 1, 32);
            float w2 = __shfl(w, i + 2, 32), w3 = __shfl(w, i + 3, 32);
            float4 h0 = ld4(Hlin + (size_t)s0 * 128 + lane * 4);
            float4 h1 = ld4(Hlin + (size_t)s1 * 128 + lane * 4);
            float4 h2 = ld4(Hlin + (size_t)s2 * 128 + lane * 4);
            float4 h3 = ld4(Hlin + (size_t)s3 * 128 + lane * 4);
            acc.x += h0.x * w0; acc.y += h0.y * w0; acc.z += h0.z * w0; acc.w += h0.w * w0;
            acc.x += h1.x * w1; acc.y += h1.y * w1; acc.z += h1.z * w1; acc.w += h1.w * w1;
            acc.x += h2.x * w2; acc.y += h2.y * w2; acc.z += h2.z * w2; acc.w += h2.w * w2;
            acc.x += h3.x * w3; acc.y += h3.y * w3; acc.z += h3.z * w3; acc.w += h3.w * w3;
        }
    }
    acc.x = acc.x >= 0.f ? acc.x : alpha * acc.x;
    acc.y = acc.y >= 0.f ? acc.y : alpha * acc.y;
    acc.z = acc.z >= 0.f ? acc.z : alpha * acc.z;
    acc.w = acc.w >= 0.f ? acc.w : alpha * acc.w;
    *(float4*)(Out + (size_t)g * 128 + lane * 4) = acc;
}

// ---------------------------------------------------------------------------
extern "C" void kernel_launch(void* const* d_in, const int* in_sizes, int n_in,
                              void* d_out, int out_size, void* d_ws, size_t ws_size,
                              hipStream_t stream) {
    const float* x  = (const float*)d_in[0];
    const void*  ei = d_in[1];
    const float* ew = (const float*)d_in[2];
    const float* W1 = (const float*)d_in[3];
    const float* b1 = (const float*)d_in[4];
    const float* W2 = (const float*)d_in[5];
    const float* b2 = (const float*)d_in[6];
    const float* ap = (const float*)d_in[7];
    const int N = in_sizes[0] / 256;
    const int E = in_sizes[2];

    float* out1 = (float*)d_out;
    float* out2 = out1 + (size_t)N * 128;

    char* p = (char*)d_ws;
    auto alloc = [&](size_t bytes) { void* r = (void*)p; p += (bytes + 255) & ~(size_t)255; return r; };
    unsigned long long* packed = (unsigned long long*)alloc((size_t)N * 8);
    float* dinv  = (float*)alloc((size_t)N * 4);
    int*   offs  = (int*)  alloc((size_t)(N + 1) * 4);
    int*   bsum  = (int*)  alloc((size_t)((N + 255) / 256) * 4);
    int*   flag  = (int*)  alloc(256);
    int*   eint  = (int*)  alloc((size_t)2 * E * 4);
    int*   rank  = (int*)  alloc((size_t)E * 4);
    int2*  spair = (int2*) alloc((size_t)E * 8);
    float* hlin  = (float*)alloc((size_t)N * 128 * 4);

    const int nbN = (N + 255) / 256;
    const int nbE = (E + 255) / 256;
    const int nb2E = (2 * E + 255) / 256;
    const int nbE4 = (E + 1023) / 1024;

    k_detect<<<1, 256, 0, stream>>>((const int*)ei, flag);
    k_repack<<<nb2E, 256, 0, stream>>>(ei, eint, flag, 2 * E);
    k_init<<<nbN, 256, 0, stream>>>(packed, N);
    k_count<<<nbE4, 256, 0, stream>>>(eint, ew, packed, rank, E);
    k_blocksum<<<nbN, 256, 0, stream>>>(packed, bsum, N);
    k_scan_bsum<<<1, 512, 0, stream>>>(bsum, nbN);
    k_scan_final<<<nbN, 256, 0, stream>>>(packed, bsum, offs, N, E);
    k_dinv<<<nbN, 256, 0, stream>>>(packed, dinv, N);
    k_scatter<<<nbE, 256, 0, stream>>>(eint, ew, dinv, offs, rank, spair, E);

    const int gb = (N + 63) / 64;
    k_gemm<<<gb, 256, 0, stream>>>(x, W1, hlin, N, 256);
    k_agg<<<(N + 7) / 8, 256, 0, stream>>>(hlin, offs, spair, dinv, b1, ap, out1, N);
    k_gemm<<<gb, 256, 0, stream>>>(out1, W2, hlin, N, 128);
    k_agg<<<(N + 7) / 8, 256, 0, stream>>>(hlin, offs, spair, dinv, b2, ap, out2, N);
}

// Round 4
// 341.341 us; speedup vs baseline: 1.9671x; 1.5077x over previous
//
#include <hip/hip_runtime.h>

// ---------------------------------------------------------------------------
// GCN 2-layer: h1 = prelu(gcn(x,W1,b1)), h2 = prelu(gcn(h1,W2,b2))
// CSR build with ONE packed 64-bit atomic per edge; atomic-free scatter.
// h stored bf16 (halves gather traffic); GEMM = MFMA 16x16x32 bf16 with
// fp32 accumulate; pull aggregation gathers bf16 rows, fp32 accumulate,
// bias+PReLU fused into the write.
// ---------------------------------------------------------------------------

static __device__ __forceinline__ float4 ld4(const float* p) { return *(const float4*)p; }

static __device__ __forceinline__ unsigned short f2bf(float f) {
    unsigned u = __float_as_uint(f);
    u += 0x7fff + ((u >> 16) & 1);          // round-to-nearest-even
    return (unsigned short)(u >> 16);
}
static __device__ __forceinline__ float bf2f(unsigned short h) {
    return __uint_as_float(((unsigned)h) << 16);
}

typedef __attribute__((ext_vector_type(8))) short short8v;
typedef __attribute__((ext_vector_type(4))) float f32x4;

#define DEG_MASK ((1ULL << 40) - 1)

// --- edge_index dtype hedge: detect int64 vs int32 -------------------------
__global__ void k_detect(const int* ei, int* flag) {
    __shared__ int anynz;
    if (threadIdx.x == 0) anynz = 0;
    __syncthreads();
    if (ei[2 * threadIdx.x + 1] != 0) anynz = 1;
    __syncthreads();
    if (threadIdx.x == 0) *flag = (anynz == 0) ? 1 : 0;
}

__global__ __launch_bounds__(256) void k_repack(const void* ei_raw, int* eint,
                                                const int* flag, int n) {
    int i = blockIdx.x * 256 + threadIdx.x;
    if (i < n) {
        int v;
        if (*flag) v = (int)((const long long*)ei_raw)[i];
        else       v = ((const int*)ei_raw)[i];
        eint[i] = v;
    }
}

__global__ __launch_bounds__(256) void k_init(unsigned long long* packed, int N) {
    int i = blockIdx.x * 256 + threadIdx.x;
    if (i < N) packed[i] = 0ULL;
}

// --- one packed atomic per edge: rank + degree accumulate -------------------
__global__ __launch_bounds__(256) void k_count(const int* __restrict__ eint,
                                               const float* __restrict__ ew,
                                               unsigned long long* __restrict__ packed,
                                               int* __restrict__ rank, int E) {
    int base = blockIdx.x * 1024 + threadIdx.x;
    int d[4]; unsigned long long inc[4]; bool ok[4];
    #pragma unroll
    for (int u = 0; u < 4; ++u) {
        int e = base + u * 256;
        ok[u] = e < E;
        if (ok[u]) {
            d[u] = eint[E + e];
            float w = ew[e];
            inc[u] = (1ULL << 40) | (unsigned long long)(w * 4294967296.0f);
        }
    }
    unsigned long long old[4];
    #pragma unroll
    for (int u = 0; u < 4; ++u)
        if (ok[u]) old[u] = atomicAdd(&packed[d[u]], inc[u]);
    #pragma unroll
    for (int u = 0; u < 4; ++u)
        if (ok[u]) rank[base + u * 256] = (int)(old[u] >> 40);
}

__global__ __launch_bounds__(256) void k_dinv(const unsigned long long* packed,
                                              float* dinv, int N) {
    int i = blockIdx.x * 256 + threadIdx.x;
    if (i < N) {
        float dg = 1.0f + (float)(packed[i] & DEG_MASK) * 2.3283064365386963e-10f;
        dinv[i] = rsqrtf(dg);
    }
}

// --- scan of counts (from packed high bits) --------------------------------
__global__ __launch_bounds__(256) void k_blocksum(const unsigned long long* packed,
                                                  int* bsum, int N) {
    int i = blockIdx.x * 256 + threadIdx.x;
    int v = i < N ? (int)(packed[i] >> 40) : 0;
    for (int d = 32; d > 0; d >>= 1) v += __shfl_down(v, d, 64);
    __shared__ int wsum[4];
    int lane = threadIdx.x & 63, wid = threadIdx.x >> 6;
    if (lane == 0) wsum[wid] = v;
    __syncthreads();
    if (threadIdx.x == 0) bsum[blockIdx.x] = wsum[0] + wsum[1] + wsum[2] + wsum[3];
}

__global__ __launch_bounds__(512) void k_scan_bsum(int* bsum, int nb) {
    int t = threadIdx.x;
    int v = (t < nb) ? bsum[t] : 0;
    int orig = v;
    int lane = t & 63, wid = t >> 6;
    for (int d = 1; d < 64; d <<= 1) { int n = __shfl_up(v, d, 64); if (lane >= d) v += n; }
    __shared__ int wsum[8];
    if (lane == 63) wsum[wid] = v;
    __syncthreads();
    int woff = 0;
    for (int w = 0; w < 8; ++w) if (w < wid) woff += wsum[w];
    if (t < nb) bsum[t] = v - orig + woff;   // exclusive
}

__global__ __launch_bounds__(256) void k_scan_final(const unsigned long long* packed,
                                                    const int* bsum,
                                                    int* offs, int N, int E) {
    int b = blockIdx.x, t = threadIdx.x;
    int i = b * 256 + t;
    int v = (i < N) ? (int)(packed[i] >> 40) : 0;
    int orig = v;
    int lane = t & 63, wid = t >> 6;
    for (int d = 1; d < 64; d <<= 1) { int n = __shfl_up(v, d, 64); if (lane >= d) v += n; }
    __shared__ int wsum[4];
    if (lane == 63) wsum[wid] = v;
    __syncthreads();
    int woff = bsum[b];
    for (int w = 0; w < 4; ++w) if (w < wid) woff += wsum[w];
    if (i < N) offs[i] = v - orig + woff;
    if (i == 0) offs[N] = E;
}

// --- atomic-free scatter: position = offs[dst] + rank[e] -------------------
__global__ __launch_bounds__(256) void k_scatter(const int* __restrict__ eint,
                                                 const float* __restrict__ ew,
                                                 const float* __restrict__ dinv,
                                                 const int* __restrict__ offs,
                                                 const int* __restrict__ rank,
                                                 int2* __restrict__ spair, int E) {
    int e = blockIdx.x * 256 + threadIdx.x;
    if (e < E) {
        int s = eint[e], d = eint[E + e];
        int p = offs[d] + rank[e];
        float nrm = dinv[s] * ew[e] * dinv[d];
        int2 v; v.x = s; v.y = __float_as_int(nrm);
        spair[p] = v;
    }
}

// --- MFMA bf16 GEMM: Hb[M,128](bf16) = X[M,K](f32) @ W[128,K](f32)^T -------
// Block = 256 thr (4 waves), 64 rows/block, each wave owns 16 rows x 128 cols.
// W staged once in LDS as bf16, k-major, XOR-swizzled (elem ^= (row&7)<<3)
// to break the 16-way bank conflict of the 512B/256B row stride.
template <int K>
__global__ __launch_bounds__(256) void k_gemm(const float* __restrict__ X,
                                              const float* __restrict__ W,
                                              unsigned short* __restrict__ Hb,
                                              int M) {
    __shared__ unsigned short Wlds[128 * K];
    int tid = threadIdx.x;
    // stage W (fp32 -> bf16), swizzled
    for (int i = tid * 4; i < 128 * K; i += 1024) {
        float4 w4 = ld4(W + i);
        int r = i / K;                       // compile-time K -> shift
        int si = i ^ ((r & 7) << 3);
        ushort4 v;
        v.x = f2bf(w4.x); v.y = f2bf(w4.y); v.z = f2bf(w4.z); v.w = f2bf(w4.w);
        *(ushort4*)&Wlds[si] = v;
    }
    __syncthreads();

    int wave = tid >> 6, lane = tid & 63;
    int row0 = blockIdx.x * 64 + wave * 16;
    int arow = row0 + (lane & 15);
    if (arow >= M) arow = M - 1;
    int kchunk = (lane >> 4) * 8;
    const float* xp = X + (size_t)arow * K + kchunk;

    f32x4 acc[8] = {};
    for (int ks = 0; ks < K; ks += 32) {
        float4 a0 = ld4(xp + ks), a1 = ld4(xp + ks + 4);
        short8v af;
        af[0] = (short)f2bf(a0.x); af[1] = (short)f2bf(a0.y);
        af[2] = (short)f2bf(a0.z); af[3] = (short)f2bf(a0.w);
        af[4] = (short)f2bf(a1.x); af[5] = (short)f2bf(a1.y);
        af[6] = (short)f2bf(a1.z); af[7] = (short)f2bf(a1.w);
        #pragma unroll
        for (int nt = 0; nt < 8; ++nt) {
            int wr = nt * 16 + (lane & 15);
            int idx = wr * K + ks + kchunk;
            idx ^= ((wr & 7) << 3);
            short8v bfv = *(const short8v*)&Wlds[idx];
            acc[nt] = __builtin_amdgcn_mfma_f32_16x16x32_bf16(af, bfv, acc[nt], 0, 0, 0);
        }
    }
    // C/D: col = lane&15, row = (lane>>4)*4 + reg   [m89-verified]
    int orow0 = row0 + (lane >> 4) * 4;
    #pragma unroll
    for (int nt = 0; nt < 8; ++nt) {
        int col = nt * 16 + (lane & 15);
        #pragma unroll
        for (int j = 0; j < 4; ++j) {
            int r = orow0 + j;
            if (r < M) Hb[(size_t)r * 128 + col] = f2bf(acc[nt][j]);
        }
    }
}

// --- pull aggregation (bf16 rows) + bias + PReLU ---------------------------
__global__ __launch_bounds__(256) void k_agg(const unsigned short* __restrict__ Hb,
                                             const int* __restrict__ offs,
                                             const int2* __restrict__ spair,
                                             const float* __restrict__ dinv,
                                             const float* __restrict__ bias,
                                             const float* __restrict__ a_ptr,
                                             float* __restrict__ Out, int N) {
    int g = blockIdx.x * 8 + (threadIdx.x >> 5);
    int lane = threadIdx.x & 31;
    if (g >= N) return;
    float alpha = a_ptr[0];
    float di = dinv[g];
    float4 acc = ld4(bias + lane * 4);
    ushort4 hv = *(const ushort4*)(Hb + (size_t)g * 128 + lane * 4);
    float sw = di * di;
    acc.x += bf2f(hv.x) * sw; acc.y += bf2f(hv.y) * sw;
    acc.z += bf2f(hv.z) * sw; acc.w += bf2f(hv.w) * sw;
    int j0 = offs[g], j1 = offs[g + 1];
    for (int jb = j0; jb < j1; jb += 32) {
        int j = jb + lane;
        int s = 0; float w = 0.f;
        if (j < j1) { int2 sp = spair[j]; s = sp.x; w = __int_as_float(sp.y); }
        int cnt = j1 - jb; if (cnt > 32) cnt = 32;
        int full = cnt & ~3, i = 0;
        for (; i < full; i += 4) {
            int   s0 = __shfl(s, i,     32), s1 = __shfl(s, i + 1, 32);
            int   s2 = __shfl(s, i + 2, 32), s3 = __shfl(s, i + 3, 32);
            float w0 = __shfl(w, i,     32), w1 = __shfl(w, i + 1, 32);
            float w2 = __shfl(w, i + 2, 32), w3 = __shfl(w, i + 3, 32);
            ushort4 h0 = *(const ushort4*)(Hb + (size_t)s0 * 128 + lane * 4);
            ushort4 h1 = *(const ushort4*)(Hb + (size_t)s1 * 128 + lane * 4);
            ushort4 h2 = *(const ushort4*)(Hb + (size_t)s2 * 128 + lane * 4);
            ushort4 h3 = *(const ushort4*)(Hb + (size_t)s3 * 128 + lane * 4);
            acc.x += bf2f(h0.x) * w0; acc.y += bf2f(h0.y) * w0;
            acc.z += bf2f(h0.z) * w0; acc.w += bf2f(h0.w) * w0;
            acc.x += bf2f(h1.x) * w1; acc.y += bf2f(h1.y) * w1;
            acc.z += bf2f(h1.z) * w1; acc.w += bf2f(h1.w) * w1;
            acc.x += bf2f(h2.x) * w2; acc.y += bf2f(h2.y) * w2;
            acc.z += bf2f(h2.z) * w2; acc.w += bf2f(h2.w) * w2;
            acc.x += bf2f(h3.x) * w3; acc.y += bf2f(h3.y) * w3;
            acc.z += bf2f(h3.z) * w3; acc.w += bf2f(h3.w) * w3;
        }
        for (; i < cnt; ++i) {
            int   sv = __shfl(s, i, 32);
            float wv = __shfl(w, i, 32);
            ushort4 h4 = *(const ushort4*)(Hb + (size_t)sv * 128 + lane * 4);
            acc.x += bf2f(h4.x) * wv; acc.y += bf2f(h4.y) * wv;
            acc.z += bf2f(h4.z) * wv; acc.w += bf2f(h4.w) * wv;
        }
    }
    acc.x = acc.x >= 0.f ? acc.x : alpha * acc.x;
    acc.y = acc.y >= 0.f ? acc.y : alpha * acc.y;
    acc.z = acc.z >= 0.f ? acc.z : alpha * acc.z;
    acc.w = acc.w >= 0.f ? acc.w : alpha * acc.w;
    *(float4*)(Out + (size_t)g * 128 + lane * 4) = acc;
}

// ---------------------------------------------------------------------------
extern "C" void kernel_launch(void* const* d_in, const int* in_sizes, int n_in,
                              void* d_out, int out_size, void* d_ws, size_t ws_size,
                              hipStream_t stream) {
    const float* x  = (const float*)d_in[0];
    const void*  ei = d_in[1];
    const float* ew = (const float*)d_in[2];
    const float* W1 = (const float*)d_in[3];
    const float* b1 = (const float*)d_in[4];
    const float* W2 = (const float*)d_in[5];
    const float* b2 = (const float*)d_in[6];
    const float* ap = (const float*)d_in[7];
    const int N = in_sizes[0] / 256;
    const int E = in_sizes[2];

    float* out1 = (float*)d_out;
    float* out2 = out1 + (size_t)N * 128;

    char* p = (char*)d_ws;
    auto alloc = [&](size_t bytes) { void* r = (void*)p; p += (bytes + 255) & ~(size_t)255; return r; };
    unsigned long long* packed = (unsigned long long*)alloc((size_t)N * 8);
    float* dinv  = (float*)alloc((size_t)N * 4);
    int*   offs  = (int*)  alloc((size_t)(N + 1) * 4);
    int*   bsum  = (int*)  alloc((size_t)((N + 255) / 256) * 4);
    int*   flag  = (int*)  alloc(256);
    int*   eint  = (int*)  alloc((size_t)2 * E * 4);
    int*   rank  = (int*)  alloc((size_t)E * 4);
    int2*  spair = (int2*) alloc((size_t)E * 8);
    unsigned short* hb = (unsigned short*)alloc((size_t)N * 128 * 2);

    const int nbN = (N + 255) / 256;
    const int nbE = (E + 255) / 256;
    const int nb2E = (2 * E + 255) / 256;
    const int nbE4 = (E + 1023) / 1024;

    k_detect<<<1, 256, 0, stream>>>((const int*)ei, flag);
    k_repack<<<nb2E, 256, 0, stream>>>(ei, eint, flag, 2 * E);
    k_init<<<nbN, 256, 0, stream>>>(packed, N);
    k_count<<<nbE4, 256, 0, stream>>>(eint, ew, packed, rank, E);
    k_blocksum<<<nbN, 256, 0, stream>>>(packed, bsum, N);
    k_scan_bsum<<<1, 512, 0, stream>>>(bsum, nbN);
    k_scan_final<<<nbN, 256, 0, stream>>>(packed, bsum, offs, N, E);
    k_dinv<<<nbN, 256, 0, stream>>>(packed, dinv, N);
    k_scatter<<<nbE, 256, 0, stream>>>(eint, ew, dinv, offs, rank, spair, E);

    const int gb = (N + 63) / 64;
    k_gemm<256><<<gb, 256, 0, stream>>>(x, W1, hb, N);
    k_agg<<<(N + 7) / 8, 256, 0, stream>>>(hb, offs, spair, dinv, b1, ap, out1, N);
    k_gemm<128><<<gb, 256, 0, stream>>>(out1, W2, hb, N);
    k_agg<<<(N + 7) / 8, 256, 0, stream>>>(hb, offs, spair, dinv, b2, ap, out2, N);
}

// Round 5
// 312.955 us; speedup vs baseline: 2.1455x; 1.0907x over previous
//
#include <hip/hip_runtime.h>

// ---------------------------------------------------------------------------
// GCN 2-layer: h1 = prelu(gcn(x,W1,b1)), h2 = prelu(gcn(h1,W2,b2))
// CSR build with ONE packed 64-bit atomic per edge; atomic-free scatter.
// h stored bf16; GEMM = LDS-free MFMA 16x16x32 bf16 with pre-packed
// B-fragment weights (one-time pack kernel), 32 rows/wave, fp32 accum.
// Pull aggregation gathers bf16 rows, fp32 accumulate, bias+PReLU fused.
// ---------------------------------------------------------------------------

static __device__ __forceinline__ float4 ld4(const float* p) { return *(const float4*)p; }

static __device__ __forceinline__ unsigned short f2bf(float f) {
    unsigned u = __float_as_uint(f);
    u += 0x7fff + ((u >> 16) & 1);          // round-to-nearest-even
    return (unsigned short)(u >> 16);
}
static __device__ __forceinline__ float bf2f(unsigned short h) {
    return __uint_as_float(((unsigned)h) << 16);
}

typedef __attribute__((ext_vector_type(8))) short short8v;
typedef __attribute__((ext_vector_type(4))) float f32x4;

#define DEG_MASK ((1ULL << 40) - 1)

// --- edge_index dtype hedge: detect int64 vs int32 -------------------------
__global__ void k_detect(const int* ei, int* flag) {
    __shared__ int anynz;
    if (threadIdx.x == 0) anynz = 0;
    __syncthreads();
    if (ei[2 * threadIdx.x + 1] != 0) anynz = 1;
    __syncthreads();
    if (threadIdx.x == 0) *flag = (anynz == 0) ? 1 : 0;
}

__global__ __launch_bounds__(256) void k_repack(const void* ei_raw, int* eint,
                                                const int* flag, int n) {
    int i = blockIdx.x * 256 + threadIdx.x;
    if (i < n) {
        int v;
        if (*flag) v = (int)((const long long*)ei_raw)[i];
        else       v = ((const int*)ei_raw)[i];
        eint[i] = v;
    }
}

__global__ __launch_bounds__(256) void k_init(unsigned long long* packed, int N) {
    int i = blockIdx.x * 256 + threadIdx.x;
    if (i < N) packed[i] = 0ULL;
}

// --- one packed atomic per edge: rank + degree accumulate -------------------
__global__ __launch_bounds__(256) void k_count(const int* __restrict__ eint,
                                               const float* __restrict__ ew,
                                               unsigned long long* __restrict__ packed,
                                               int* __restrict__ rank, int E) {
    int base = blockIdx.x * 1024 + threadIdx.x;
    int d[4]; unsigned long long inc[4]; bool ok[4];
    #pragma unroll
    for (int u = 0; u < 4; ++u) {
        int e = base + u * 256;
        ok[u] = e < E;
        if (ok[u]) {
            d[u] = eint[E + e];
            float w = ew[e];
            inc[u] = (1ULL << 40) | (unsigned long long)(w * 4294967296.0f);
        }
    }
    unsigned long long old[4];
    #pragma unroll
    for (int u = 0; u < 4; ++u)
        if (ok[u]) old[u] = atomicAdd(&packed[d[u]], inc[u]);
    #pragma unroll
    for (int u = 0; u < 4; ++u)
        if (ok[u]) rank[base + u * 256] = (int)(old[u] >> 40);
}

__global__ __launch_bounds__(256) void k_dinv(const unsigned long long* packed,
                                              float* dinv, int N) {
    int i = blockIdx.x * 256 + threadIdx.x;
    if (i < N) {
        float dg = 1.0f + (float)(packed[i] & DEG_MASK) * 2.3283064365386963e-10f;
        dinv[i] = rsqrtf(dg);
    }
}

// --- scan of counts (from packed high bits) --------------------------------
__global__ __launch_bounds__(256) void k_blocksum(const unsigned long long* packed,
                                                  int* bsum, int N) {
    int i = blockIdx.x * 256 + threadIdx.x;
    int v = i < N ? (int)(packed[i] >> 40) : 0;
    for (int d = 32; d > 0; d >>= 1) v += __shfl_down(v, d, 64);
    __shared__ int wsum[4];
    int lane = threadIdx.x & 63, wid = threadIdx.x >> 6;
    if (lane == 0) wsum[wid] = v;
    __syncthreads();
    if (threadIdx.x == 0) bsum[blockIdx.x] = wsum[0] + wsum[1] + wsum[2] + wsum[3];
}

__global__ __launch_bounds__(512) void k_scan_bsum(int* bsum, int nb) {
    int t = threadIdx.x;
    int v = (t < nb) ? bsum[t] : 0;
    int orig = v;
    int lane = t & 63, wid = t >> 6;
    for (int d = 1; d < 64; d <<= 1) { int n = __shfl_up(v, d, 64); if (lane >= d) v += n; }
    __shared__ int wsum[8];
    if (lane == 63) wsum[wid] = v;
    __syncthreads();
    int woff = 0;
    for (int w = 0; w < 8; ++w) if (w < wid) woff += wsum[w];
    if (t < nb) bsum[t] = v - orig + woff;   // exclusive
}

__global__ __launch_bounds__(256) void k_scan_final(const unsigned long long* packed,
                                                    const int* bsum,
                                                    int* offs, int N, int E) {
    int b = blockIdx.x, t = threadIdx.x;
    int i = b * 256 + t;
    int v = (i < N) ? (int)(packed[i] >> 40) : 0;
    int orig = v;
    int lane = t & 63, wid = t >> 6;
    for (int d = 1; d < 64; d <<= 1) { int n = __shfl_up(v, d, 64); if (lane >= d) v += n; }
    __shared__ int wsum[4];
    if (lane == 63) wsum[wid] = v;
    __syncthreads();
    int woff = bsum[b];
    for (int w = 0; w < 4; ++w) if (w < wid) woff += wsum[w];
    if (i < N) offs[i] = v - orig + woff;
    if (i == 0) offs[N] = E;
}

// --- atomic-free scatter: position = offs[dst] + rank[e] -------------------
__global__ __launch_bounds__(256) void k_scatter(const int* __restrict__ eint,
                                                 const float* __restrict__ ew,
                                                 const float* __restrict__ dinv,
                                                 const int* __restrict__ offs,
                                                 const int* __restrict__ rank,
                                                 int2* __restrict__ spair, int E) {
    int e = blockIdx.x * 256 + threadIdx.x;
    if (e < E) {
        int s = eint[e], d = eint[E + e];
        int p = offs[d] + rank[e];
        float nrm = dinv[s] * ew[e] * dinv[d];
        int2 v; v.x = s; v.y = __float_as_int(nrm);
        spair[p] = v;
    }
}

// --- one-time W pack: fp32 [128][K] -> bf16 B-fragment layout --------------
// element (col,k) -> Bp[((nt*(K/32)+ks)*64 + lane)*8 + j]
//   nt=col>>4, ks=k>>5, lane=(col&15)|(((k>>3)&3)<<4), j=k&7
template <int K>
__global__ __launch_bounds__(256) void k_packW(const float* __restrict__ W,
                                               unsigned short* __restrict__ Bp) {
    int t = blockIdx.x * 256 + threadIdx.x;
    if (t < 128 * K) {
        int col = t / K, k = t % K;
        int nt = col >> 4, ks = k >> 5;
        int lane = (col & 15) | (((k >> 3) & 3) << 4);
        int j = k & 7;
        Bp[(((size_t)nt * (K / 32) + ks) * 64 + lane) * 8 + j] = f2bf(W[t]);
    }
}

// --- LDS-free MFMA GEMM: Hb[M,128](bf16) = X[M,K](f32) @ packedW^T ---------
// 128 thr = 2 waves; each wave: 32 rows (2 A row-groups) x 128 cols.
template <int K>
__global__ __launch_bounds__(128) void k_gemm(const float* __restrict__ X,
                                              const unsigned short* __restrict__ Bp,
                                              unsigned short* __restrict__ Hb,
                                              int M) {
    constexpr int KS = K / 32;
    int wave = threadIdx.x >> 6, lane = threadIdx.x & 63;
    int row0 = blockIdx.x * 64 + wave * 32;
    int r0 = row0 + (lane & 15);      if (r0 >= M) r0 = M - 1;
    int r1 = row0 + 16 + (lane & 15); if (r1 >= M) r1 = M - 1;
    int kc = (lane >> 4) * 8;
    const float* x0 = X + (size_t)r0 * K + kc;
    const float* x1 = X + (size_t)r1 * K + kc;

    f32x4 acc[2][8] = {};
    #pragma unroll 2
    for (int ks = 0; ks < KS; ++ks) {
        float4 a0 = ld4(x0 + ks * 32), a1 = ld4(x0 + ks * 32 + 4);
        float4 c0 = ld4(x1 + ks * 32), c1 = ld4(x1 + ks * 32 + 4);
        short8v af0, af1;
        af0[0] = (short)f2bf(a0.x); af0[1] = (short)f2bf(a0.y);
        af0[2] = (short)f2bf(a0.z); af0[3] = (short)f2bf(a0.w);
        af0[4] = (short)f2bf(a1.x); af0[5] = (short)f2bf(a1.y);
        af0[6] = (short)f2bf(a1.z); af0[7] = (short)f2bf(a1.w);
        af1[0] = (short)f2bf(c0.x); af1[1] = (short)f2bf(c0.y);
        af1[2] = (short)f2bf(c0.z); af1[3] = (short)f2bf(c0.w);
        af1[4] = (short)f2bf(c1.x); af1[5] = (short)f2bf(c1.y);
        af1[6] = (short)f2bf(c1.z); af1[7] = (short)f2bf(c1.w);
        #pragma unroll
        for (int nt = 0; nt < 8; ++nt) {
            short8v bf = *(const short8v*)&Bp[(((size_t)nt * KS + ks) * 64 + lane) * 8];
            acc[0][nt] = __builtin_amdgcn_mfma_f32_16x16x32_bf16(af0, bf, acc[0][nt], 0, 0, 0);
            acc[1][nt] = __builtin_amdgcn_mfma_f32_16x16x32_bf16(af1, bf, acc[1][nt], 0, 0, 0);
        }
    }
    // C/D: col = lane&15, row = (lane>>4)*4 + reg   [m89-verified]
    #pragma unroll
    for (int rg = 0; rg < 2; ++rg) {
        int orow0 = row0 + rg * 16 + (lane >> 4) * 4;
        #pragma unroll
        for (int nt = 0; nt < 8; ++nt) {
            int col = nt * 16 + (lane & 15);
            #pragma unroll
            for (int j = 0; j < 4; ++j) {
                int r = orow0 + j;
                if (r < M) Hb[(size_t)r * 128 + col] = f2bf(acc[rg][nt][j]);
            }
        }
    }
}

// --- pull aggregation (bf16 rows) + bias + PReLU ---------------------------
__global__ __launch_bounds__(256) void k_agg(const unsigned short* __restrict__ Hb,
                                             const int* __restrict__ offs,
                                             const int2* __restrict__ spair,
                                             const float* __restrict__ dinv,
                                             const float* __restrict__ bias,
                                             const float* __restrict__ a_ptr,
                                             float* __restrict__ Out, int N) {
    int g = blockIdx.x * 8 + (threadIdx.x >> 5);
    int lane = threadIdx.x & 31;
    if (g >= N) return;
    float alpha = a_ptr[0];
    float di = dinv[g];
    float4 acc = ld4(bias + lane * 4);
    ushort4 hv = *(const ushort4*)(Hb + (size_t)g * 128 + lane * 4);
    float sw = di * di;
    acc.x += bf2f(hv.x) * sw; acc.y += bf2f(hv.y) * sw;
    acc.z += bf2f(hv.z) * sw; acc.w += bf2f(hv.w) * sw;
    int j0 = offs[g], j1 = offs[g + 1];
    for (int jb = j0; jb < j1; jb += 32) {
        int j = jb + lane;
        int s = 0; float w = 0.f;
        if (j < j1) { int2 sp = spair[j]; s = sp.x; w = __int_as_float(sp.y); }
        int cnt = j1 - jb; if (cnt > 32) cnt = 32;
        int full = cnt & ~3, i = 0;
        for (; i < full; i += 4) {
            int   s0 = __shfl(s, i,     32), s1 = __shfl(s, i + 1, 32);
            int   s2 = __shfl(s, i + 2, 32), s3 = __shfl(s, i + 3, 32);
            float w0 = __shfl(w, i,     32), w1 = __shfl(w, i + 1, 32);
            float w2 = __shfl(w, i + 2, 32), w3 = __shfl(w, i + 3, 32);
            ushort4 h0 = *(const ushort4*)(Hb + (size_t)s0 * 128 + lane * 4);
            ushort4 h1 = *(const ushort4*)(Hb + (size_t)s1 * 128 + lane * 4);
            ushort4 h2 = *(const ushort4*)(Hb + (size_t)s2 * 128 + lane * 4);
            ushort4 h3 = *(const ushort4*)(Hb + (size_t)s3 * 128 + lane * 4);
            acc.x += bf2f(h0.x) * w0; acc.y += bf2f(h0.y) * w0;
            acc.z += bf2f(h0.z) * w0; acc.w += bf2f(h0.w) * w0;
            acc.x += bf2f(h1.x) * w1; acc.y += bf2f(h1.y) * w1;
            acc.z += bf2f(h1.z) * w1; acc.w += bf2f(h1.w) * w1;
            acc.x += bf2f(h2.x) * w2; acc.y += bf2f(h2.y) * w2;
            acc.z += bf2f(h2.z) * w2; acc.w += bf2f(h2.w) * w2;
            acc.x += bf2f(h3.x) * w3; acc.y += bf2f(h3.y) * w3;
            acc.z += bf2f(h3.z) * w3; acc.w += bf2f(h3.w) * w3;
        }
        for (; i < cnt; ++i) {
            int   sv = __shfl(s, i, 32);
            float wv = __shfl(w, i, 32);
            ushort4 h4 = *(const ushort4*)(Hb + (size_t)sv * 128 + lane * 4);
            acc.x += bf2f(h4.x) * wv; acc.y += bf2f(h4.y) * wv;
            acc.z += bf2f(h4.z) * wv; acc.w += bf2f(h4.w) * wv;
        }
    }
    acc.x = acc.x >= 0.f ? acc.x : alpha * acc.x;
    acc.y = acc.y >= 0.f ? acc.y : alpha * acc.y;
    acc.z = acc.z >= 0.f ? acc.z : alpha * acc.z;
    acc.w = acc.w >= 0.f ? acc.w : alpha * acc.w;
    *(float4*)(Out + (size_t)g * 128 + lane * 4) = acc;
}

// ---------------------------------------------------------------------------
extern "C" void kernel_launch(void* const* d_in, const int* in_sizes, int n_in,
                              void* d_out, int out_size, void* d_ws, size_t ws_size,
                              hipStream_t stream) {
    const float* x  = (const float*)d_in[0];
    const void*  ei = d_in[1];
    const float* ew = (const float*)d_in[2];
    const float* W1 = (const float*)d_in[3];
    const float* b1 = (const float*)d_in[4];
    const float* W2 = (const float*)d_in[5];
    const float* b2 = (const float*)d_in[6];
    const float* ap = (const float*)d_in[7];
    const int N = in_sizes[0] / 256;
    const int E = in_sizes[2];

    float* out1 = (float*)d_out;
    float* out2 = out1 + (size_t)N * 128;

    char* p = (char*)d_ws;
    auto alloc = [&](size_t bytes) { void* r = (void*)p; p += (bytes + 255) & ~(size_t)255; return r; };
    unsigned long long* packed = (unsigned long long*)alloc((size_t)N * 8);
    float* dinv  = (float*)alloc((size_t)N * 4);
    int*   offs  = (int*)  alloc((size_t)(N + 1) * 4);
    int*   bsum  = (int*)  alloc((size_t)((N + 255) / 256) * 4);
    int*   flag  = (int*)  alloc(256);
    int*   eint  = (int*)  alloc((size_t)2 * E * 4);
    int*   rank  = (int*)  alloc((size_t)E * 4);
    int2*  spair = (int2*) alloc((size_t)E * 8);
    unsigned short* hb  = (unsigned short*)alloc((size_t)N * 128 * 2);
    unsigned short* bp1 = (unsigned short*)alloc((size_t)128 * 256 * 2);
    unsigned short* bp2 = (unsigned short*)alloc((size_t)128 * 128 * 2);

    const int nbN = (N + 255) / 256;
    const int nbE = (E + 255) / 256;
    const int nb2E = (2 * E + 255) / 256;
    const int nbE4 = (E + 1023) / 1024;

    k_detect<<<1, 256, 0, stream>>>((const int*)ei, flag);
    k_repack<<<nb2E, 256, 0, stream>>>(ei, eint, flag, 2 * E);
    k_init<<<nbN, 256, 0, stream>>>(packed, N);
    k_packW<256><<<128, 256, 0, stream>>>(W1, bp1);
    k_packW<128><<<64, 256, 0, stream>>>(W2, bp2);
    k_count<<<nbE4, 256, 0, stream>>>(eint, ew, packed, rank, E);
    k_blocksum<<<nbN, 256, 0, stream>>>(packed, bsum, N);
    k_scan_bsum<<<1, 512, 0, stream>>>(bsum, nbN);
    k_scan_final<<<nbN, 256, 0, stream>>>(packed, bsum, offs, N, E);
    k_dinv<<<nbN, 256, 0, stream>>>(packed, dinv, N);
    k_scatter<<<nbE, 256, 0, stream>>>(eint, ew, dinv, offs, rank, spair, E);

    const int gb = (N + 63) / 64;
    k_gemm<256><<<gb, 128, 0, stream>>>(x, bp1, hb, N);
    k_agg<<<(N + 7) / 8, 256, 0, stream>>>(hb, offs, spair, dinv, b1, ap, out1, N);
    k_gemm<128><<<gb, 128, 0, stream>>>(out1, bp2, hb, N);
    k_agg<<<(N + 7) / 8, 256, 0, stream>>>(hb, offs, spair, dinv, b2, ap, out2, N);
}